// Round 1
// baseline (225.802 us; speedup 1.0000x reference)
//
#include <hip/hip_runtime.h>
#include <hip/hip_bf16.h>
#include <stdint.h>

// ---------- types ----------
typedef __bf16 bf16_8t __attribute__((ext_vector_type(8)));
typedef float  f32x4   __attribute__((ext_vector_type(4)));

__device__ __forceinline__ float u2f(unsigned short u) {
  union { uint32_t i; float f; } c; c.i = ((uint32_t)u) << 16; return c.f;
}
__device__ __forceinline__ unsigned short f2bf(float f) {
  union { float f; uint32_t i; } c; c.f = f;
  uint32_t u = c.i;
  u += 0x7FFFu + ((u >> 16) & 1u);   // round-to-nearest-even
  return (unsigned short)(u >> 16);
}

// ---------- f32 -> bf16 conversion (4 elems/thread) ----------
__global__ __launch_bounds__(256) void cvt_f32_bf16(const float* __restrict__ in,
                                                    unsigned short* __restrict__ out,
                                                    int n4) {
  int i = blockIdx.x * 256 + threadIdx.x;
  if (i >= n4) return;
  float4 f = reinterpret_cast<const float4*>(in)[i];
  ushort4 u;
  u.x = f2bf(f.x); u.y = f2bf(f.y); u.z = f2bf(f.z); u.w = f2bf(f.w);
  reinterpret_cast<ushort4*>(out)[i] = u;
}

// ---------- bf16 GEMM, C[m,n] = sum_k A[m,k]*B[n,k]  (A: MxK, B: NxK, both row-major)
// 128x128 tile, 4 waves (2x2), each wave 64x64 = 4x4 frags of 16x16, MFMA 16x16x32.
template<bool BF16_OUT>
__global__ __launch_bounds__(256) void gemm_bt(
    const unsigned short* __restrict__ A,
    const unsigned short* __restrict__ B,
    unsigned short* __restrict__ Cb,
    float* __restrict__ Cf,
    const float* __restrict__ bias,
    int M, int N, int K)
{
  __shared__ unsigned short As[128 * 32];
  __shared__ unsigned short Bs[128 * 32];
  const int tid  = threadIdx.x;
  const int m0   = blockIdx.x * 128;
  const int n0   = blockIdx.y * 128;
  const int wave = tid >> 6, lane = tid & 63;
  const int wr = wave >> 1, wc = wave & 1;
  const int sr = tid >> 2;           // staging row 0..63
  const int sc = (tid & 3) * 8;      // staging col (8 bf16 chunks)
  const size_t aBase0 = (size_t)(m0 + sr) * K + sc;
  const size_t aBase1 = (size_t)(m0 + 64 + sr) * K + sc;
  const size_t bBase0 = (size_t)(n0 + sr) * K + sc;
  const size_t bBase1 = (size_t)(n0 + 64 + sr) * K + sc;

  f32x4 acc[4][4];
  const f32x4 zero = {0.f, 0.f, 0.f, 0.f};
  #pragma unroll
  for (int i = 0; i < 4; ++i)
    #pragma unroll
    for (int j = 0; j < 4; ++j) acc[i][j] = zero;

  const int lr = lane & 15;
  const int lk = (lane >> 4) * 8;

  for (int kt = 0; kt < K; kt += 32) {
    int4 a0 = *reinterpret_cast<const int4*>(A + aBase0 + kt);
    int4 a1 = *reinterpret_cast<const int4*>(A + aBase1 + kt);
    int4 b0 = *reinterpret_cast<const int4*>(B + bBase0 + kt);
    int4 b1 = *reinterpret_cast<const int4*>(B + bBase1 + kt);
    __syncthreads();   // previous iteration's LDS reads done
    *reinterpret_cast<int4*>(As + sr * 32 + sc)        = a0;
    *reinterpret_cast<int4*>(As + (64 + sr) * 32 + sc) = a1;
    *reinterpret_cast<int4*>(Bs + sr * 32 + sc)        = b0;
    *reinterpret_cast<int4*>(Bs + (64 + sr) * 32 + sc) = b1;
    __syncthreads();
    bf16_8t af[4], bfr[4];
    #pragma unroll
    for (int i = 0; i < 4; ++i)
      af[i] = *reinterpret_cast<const bf16_8t*>(As + (wr * 64 + i * 16 + lr) * 32 + lk);
    #pragma unroll
    for (int j = 0; j < 4; ++j)
      bfr[j] = *reinterpret_cast<const bf16_8t*>(Bs + (wc * 64 + j * 16 + lr) * 32 + lk);
    #pragma unroll
    for (int i = 0; i < 4; ++i)
      #pragma unroll
      for (int j = 0; j < 4; ++j)
        acc[i][j] = __builtin_amdgcn_mfma_f32_16x16x32_bf16(af[i], bfr[j], acc[i][j], 0, 0, 0);
  }

  const int cr = (lane >> 4) * 4;
  const int cc = lane & 15;
  #pragma unroll
  for (int i = 0; i < 4; ++i) {
    #pragma unroll
    for (int j = 0; j < 4; ++j) {
      const int row = m0 + wr * 64 + i * 16 + cr;
      const int col = n0 + wc * 64 + j * 16 + cc;
      #pragma unroll
      for (int t = 0; t < 4; ++t) {
        if constexpr (BF16_OUT) {
          Cb[(size_t)(row + t) * N + col] = f2bf(acc[i][j][t]);
        } else {
          Cf[(size_t)(row + t) * N + col] = acc[i][j][t] + bias[col];
        }
      }
    }
  }
}

// ---------- stripe attention + LePE ----------
// qkv: 32768 x 1536 bf16 rows = (b,h,w); [q(512) | k(512) | v(512)]
// One wave per head-window (65536 total; half 0 = horizontal stripes ch 0..255,
// half 1 = vertical stripes ch 256..511). ss=8, hd=32, nh=8 per half.
__global__ __launch_bounds__(256) void attn_lepe(
    const unsigned short* __restrict__ qkv,
    const float* __restrict__ lepe_h,   // (3,3,1,256)
    const float* __restrict__ lepe_v,
    unsigned short* __restrict__ outp)  // 32768 x 512 bf16
{
  const int gw   = (int)((blockIdx.x * 256 + threadIdx.x) >> 6);
  const int lane = threadIdx.x & 63;
  const int half = gw >> 15;
  const int id   = gw & 32767;
  const int n    = id & 7;
  const int b    = id >> 12;
  int mstride, h0, w0;
  if (half == 0) {                     // horizontal: tokens run down H at fixed W
    const int wcol = (id >> 3) & 63;
    const int s    = (id >> 9) & 7;
    mstride = 64; h0 = s * 8; w0 = wcol;
  } else {                             // vertical: tokens run across W at fixed H
    const int s    = (id >> 3) & 7;
    const int hrow = (id >> 6) & 63;
    mstride = 1;  h0 = hrow; w0 = s * 8;
  }
  const int mbase = b * 4096 + h0 * 64 + w0;
  const int chan0 = half * 256 + n * 32;

  // ---- QK^T: lane = qr*8 + kr computes one logit (dot over hd=32) ----
  const int qr = lane >> 3, kr = lane & 7;
  const unsigned short* qp = qkv + (size_t)(mbase + qr * mstride) * 1536 + chan0;
  const unsigned short* kp = qkv + (size_t)(mbase + kr * mstride) * 1536 + 512 + chan0;
  float s_val = 0.f;
  #pragma unroll
  for (int c = 0; c < 4; ++c) {
    bf16_8t qv = *reinterpret_cast<const bf16_8t*>(qp + c * 8);
    bf16_8t kv = *reinterpret_cast<const bf16_8t*>(kp + c * 8);
    #pragma unroll
    for (int e = 0; e < 8; ++e) s_val += (float)qv[e] * (float)kv[e];
  }
  s_val *= 0.17677669529663687f;  // 1/sqrt(32)

  // ---- softmax over k within each 8-lane group ----
  float mx = s_val;
  mx = fmaxf(mx, __shfl_xor(mx, 1));
  mx = fmaxf(mx, __shfl_xor(mx, 2));
  mx = fmaxf(mx, __shfl_xor(mx, 4));
  float p = __expf(s_val - mx);
  float den = p;
  den += __shfl_xor(den, 1);
  den += __shfl_xor(den, 2);
  den += __shfl_xor(den, 4);
  const float a = p / den;

  // ---- PV: lane handles row qr, dims d0..d0+3 (d0 = (lane&7)*4) ----
  const int d0 = (lane & 7) * 4;
  const int gb = lane & 56;
  float o0 = 0.f, o1 = 0.f, o2 = 0.f, o3 = 0.f;
  #pragma unroll
  for (int k = 0; k < 8; ++k) {
    const float ak = __shfl(a, gb | k);
    const ushort4 vv = *reinterpret_cast<const ushort4*>(
        qkv + (size_t)(mbase + k * mstride) * 1536 + 1024 + chan0 + d0);
    o0 += ak * u2f(vv.x);
    o1 += ak * u2f(vv.y);
    o2 += ak * u2f(vv.z);
    o3 += ak * u2f(vv.w);
  }

  // ---- LePE: depthwise 3x3 on v (zero-pad SAME) at this lane's pixel ----
  const int hq = h0 + ((half == 0) ? qr : 0);
  const int wq = w0 + ((half == 0) ? 0 : qr);
  const float* lw = (half == 0) ? lepe_h : lepe_v;
  float l0 = 0.f, l1 = 0.f, l2 = 0.f, l3 = 0.f;
  #pragma unroll
  for (int dy = -1; dy <= 1; ++dy) {
    const int hh = hq + dy;
    if (hh < 0 || hh > 63) continue;
    #pragma unroll
    for (int dx = -1; dx <= 1; ++dx) {
      const int ww = wq + dx;
      if (ww < 0 || ww > 63) continue;
      const ushort4 vv = *reinterpret_cast<const ushort4*>(
          qkv + (size_t)(b * 4096 + hh * 64 + ww) * 1536 + 1024 + chan0 + d0);
      const float4 wv = *reinterpret_cast<const float4*>(
          lw + ((dy + 1) * 3 + (dx + 1)) * 256 + n * 32 + d0);
      l0 += wv.x * u2f(vv.x);
      l1 += wv.y * u2f(vv.y);
      l2 += wv.z * u2f(vv.z);
      l3 += wv.w * u2f(vv.w);
    }
  }

  const int mq = mbase + qr * mstride;
  ushort4 r;
  r.x = f2bf(o0 + l0);
  r.y = f2bf(o1 + l1);
  r.z = f2bf(o2 + l2);
  r.w = f2bf(o3 + l3);
  *reinterpret_cast<ushort4*>(outp + (size_t)mq * 512 + chan0 + d0) = r;
}

// ---------- launch ----------
extern "C" void kernel_launch(void* const* d_in, const int* in_sizes, int n_in,
                              void* d_out, int out_size, void* d_ws, size_t ws_size,
                              hipStream_t stream) {
  const float* x      = (const float*)d_in[0];   // (8, 4096, 512)
  const float* w_qkv  = (const float*)d_in[1];   // (1536, 512)
  const float* w_proj = (const float*)d_in[2];   // (512, 512)
  const float* b_proj = (const float*)d_in[3];   // (512,)
  const float* lepe_h = (const float*)d_in[4];   // (3,3,1,256)
  const float* lepe_v = (const float*)d_in[5];   // (3,3,1,256)
  float* out = (float*)d_out;                    // (8, 4096, 512) f32

  char* ws = (char*)d_ws;
  unsigned short* qkv_bf   = (unsigned short*)ws;                    // 32768*1536 bf16 (96 MB)
  unsigned short* xbf      = (unsigned short*)(ws + 100663296);      // 32768*512  bf16 (32 MB); reused as attn_out
  unsigned short* wqkv_bf  = (unsigned short*)(ws + 134217728);      // 1536*512
  unsigned short* wproj_bf = (unsigned short*)(ws + 135790592);      // 512*512

  // casts
  cvt_f32_bf16<<<16384, 256, 0, stream>>>(x, xbf, 4194304);
  cvt_f32_bf16<<<768,   256, 0, stream>>>(w_qkv, wqkv_bf, 196608);
  cvt_f32_bf16<<<256,   256, 0, stream>>>(w_proj, wproj_bf, 65536);

  // qkv = x @ w_qkv^T  -> bf16
  gemm_bt<true><<<dim3(256, 12), 256, 0, stream>>>(
      xbf, wqkv_bf, qkv_bf, nullptr, nullptr, 32768, 1536, 512);

  // stripe attention + LePE -> attn_out (overwrites xbf region; xbf is dead)
  attn_lepe<<<16384, 256, 0, stream>>>(qkv_bf, lepe_h, lepe_v, xbf);

  // out = attn_out @ w_proj^T + b_proj  -> f32
  gemm_bt<false><<<dim3(256, 4), 256, 0, stream>>>(
      xbf, wproj_bf, nullptr, out, b_proj, 32768, 512, 512);
}

// Round 3
// 224.545 us; speedup vs baseline: 1.0056x; 1.0056x over previous
//
#include <hip/hip_runtime.h>
#include <hip/hip_bf16.h>
#include <stdint.h>

// ---------- types ----------
typedef _Float16 half2v __attribute__((ext_vector_type(2)));
typedef _Float16 half8v __attribute__((ext_vector_type(8)));
typedef uint32_t u32x4  __attribute__((ext_vector_type(4)));
typedef float    f32x4  __attribute__((ext_vector_type(4)));

__device__ __forceinline__ unsigned short f2h(float f) {
  _Float16 h = (_Float16)f;
  return __builtin_bit_cast(unsigned short, h);
}
__device__ __forceinline__ half2v bch2(uint32_t u) {
  return __builtin_bit_cast(half2v, u);
}
__device__ __forceinline__ half2v pkrtz(float a, float b) {
  return __builtin_bit_cast(half2v, __builtin_amdgcn_cvt_pkrtz(a, b));
}

// async global->LDS, 16 bytes per lane. lbase must be wave-uniform.
#define GLOAD_LDS16(gsrc, lbase)                                          \
  __builtin_amdgcn_global_load_lds(                                       \
      (const __attribute__((address_space(1))) uint32_t*)(gsrc),          \
      (__attribute__((address_space(3))) uint32_t*)(lbase), 16, 0, 0)

// ---------- f32 -> f16 conversion (4 elems/thread) ----------
__global__ __launch_bounds__(256) void cvt_f32_f16(const float* __restrict__ in,
                                                   unsigned short* __restrict__ out,
                                                   int n4) {
  int i = blockIdx.x * 256 + threadIdx.x;
  if (i >= n4) return;
  float4 f = reinterpret_cast<const float4*>(in)[i];
  ushort4 u;
  u.x = f2h(f.x); u.y = f2h(f.y); u.z = f2h(f.z); u.w = f2h(f.w);
  reinterpret_cast<ushort4*>(out)[i] = u;
}

// ---------- f16 GEMM, C[m,n] = sum_k A[m,k]*B[n,k]  (A: MxK, B: NxK row-major)
// 128x128 tile, 4 waves (2x2), each wave 64x64 = 4x4 frags, MFMA 16x16x32 f16.
// Staging via global_load_lds width=16 (m97 structure).
template<bool F16_OUT>
__global__ __launch_bounds__(256) void gemm_bt(
    const unsigned short* __restrict__ A,
    const unsigned short* __restrict__ B,
    unsigned short* __restrict__ Ch,
    float* __restrict__ Cf,
    const float* __restrict__ bias,
    int M, int N, int K)
{
  __shared__ unsigned short As[128 * 32];
  __shared__ unsigned short Bs[128 * 32];
  const int tid  = threadIdx.x;
  const int m0   = blockIdx.x * 128;
  const int n0   = blockIdx.y * 128;
  const int wave = tid >> 6, lane = tid & 63;
  const int wr = wave >> 1, wc = wave & 1;
  const int sr = tid >> 2;           // staging row 0..63
  const int sc = (tid & 3) * 8;      // staging col (8 f16 = 16B)
  const size_t aBase0 = (size_t)(m0 + sr) * K + sc;
  const size_t aBase1 = (size_t)(m0 + 64 + sr) * K + sc;
  const size_t bBase0 = (size_t)(n0 + sr) * K + sc;
  const size_t bBase1 = (size_t)(n0 + 64 + sr) * K + sc;
  // per-thread LDS byte target is tid*16 -> wave-uniform base (tid&~63)*16
  char* ldsA = (char*)As + (tid & ~63) * 16;
  char* ldsB = (char*)Bs + (tid & ~63) * 16;

  f32x4 acc[4][4];
  const f32x4 zero = {0.f, 0.f, 0.f, 0.f};
  #pragma unroll
  for (int i = 0; i < 4; ++i)
    #pragma unroll
    for (int j = 0; j < 4; ++j) acc[i][j] = zero;

  const int lr = lane & 15;
  const int lk = (lane >> 4) * 8;

  for (int kt = 0; kt < K; kt += 32) {
    __syncthreads();   // previous iteration's LDS reads done
    GLOAD_LDS16(A + aBase0 + kt, ldsA);
    GLOAD_LDS16(A + aBase1 + kt, ldsA + 4096);
    GLOAD_LDS16(B + bBase0 + kt, ldsB);
    GLOAD_LDS16(B + bBase1 + kt, ldsB + 4096);
    __syncthreads();   // drains vmcnt -> LDS tiles ready
    half8v af[4], bfr[4];
    #pragma unroll
    for (int i = 0; i < 4; ++i)
      af[i] = *reinterpret_cast<const half8v*>(As + (wr * 64 + i * 16 + lr) * 32 + lk);
    #pragma unroll
    for (int j = 0; j < 4; ++j)
      bfr[j] = *reinterpret_cast<const half8v*>(Bs + (wc * 64 + j * 16 + lr) * 32 + lk);
    #pragma unroll
    for (int i = 0; i < 4; ++i)
      #pragma unroll
      for (int j = 0; j < 4; ++j)
        acc[i][j] = __builtin_amdgcn_mfma_f32_16x16x32_f16(af[i], bfr[j], acc[i][j], 0, 0, 0);
  }

  const int cr = (lane >> 4) * 4;
  const int cc = lane & 15;
  #pragma unroll
  for (int i = 0; i < 4; ++i) {
    #pragma unroll
    for (int j = 0; j < 4; ++j) {
      const int row = m0 + wr * 64 + i * 16 + cr;
      const int col = n0 + wc * 64 + j * 16 + cc;
      #pragma unroll
      for (int t = 0; t < 4; ++t) {
        if constexpr (F16_OUT) {
          Ch[(size_t)(row + t) * N + col] = f2h(acc[i][j][t]);
        } else {
          Cf[(size_t)(row + t) * N + col] = acc[i][j][t] + bias[col];
        }
      }
    }
  }
}

// ---------- stripe attention + LePE (f16 qkv) ----------
// qkv: 32768 x 1536 f16 rows = (b,h,w); [q(512) | k(512) | v(512)]
// One wave per head-window. half 0 = horizontal stripes (ch 0..255),
// half 1 = vertical (ch 256..511). ss=8, hd=32, nh=8 per half.
__global__ __launch_bounds__(256) void attn_lepe(
    const unsigned short* __restrict__ qkv,
    const float* __restrict__ lepe_h,   // (3,3,1,256) f32
    const float* __restrict__ lepe_v,
    unsigned short* __restrict__ outp)  // 32768 x 512 f16
{
  const int gw   = (int)((blockIdx.x * 256 + threadIdx.x) >> 6);
  const int lane = threadIdx.x & 63;
  const int half = gw >> 15;
  const int id   = gw & 32767;
  const int n    = id & 7;
  const int b    = id >> 12;
  int mstride, h0, w0;
  if (half == 0) {                     // horizontal: tokens run down H at fixed W
    const int wcol = (id >> 3) & 63;
    const int s    = (id >> 9) & 7;
    mstride = 64; h0 = s * 8; w0 = wcol;
  } else {                             // vertical: tokens run across W at fixed H
    const int s    = (id >> 3) & 7;
    const int hrow = (id >> 6) & 63;
    mstride = 1;  h0 = hrow; w0 = s * 8;
  }
  const int mbase = b * 4096 + h0 * 64 + w0;
  const int chan0 = half * 256 + n * 32;

  // ---- QK^T: lane = qr*8 + kr computes one logit via v_dot2_f32_f16 ----
  const int qr = lane >> 3, kr = lane & 7;
  const unsigned short* qp = qkv + (size_t)(mbase + qr * mstride) * 1536 + chan0;
  const unsigned short* kp = qkv + (size_t)(mbase + kr * mstride) * 1536 + 512 + chan0;
  float s_val = 0.f;
  #pragma unroll
  for (int c = 0; c < 4; ++c) {
    u32x4 qv = *reinterpret_cast<const u32x4*>(qp + c * 8);
    u32x4 kv = *reinterpret_cast<const u32x4*>(kp + c * 8);
    #pragma unroll
    for (int e = 0; e < 4; ++e)
      s_val = __builtin_amdgcn_fdot2(bch2(qv[e]), bch2(kv[e]), s_val, false);
  }
  s_val *= 0.17677669529663687f;  // 1/sqrt(32)

  // ---- softmax over k within each 8-lane group (no max pass: |s| bounded) ----
  float p = __expf(s_val);
  float den = p;
  den += __shfl_xor(den, 1);
  den += __shfl_xor(den, 2);
  den += __shfl_xor(den, 4);
  const float a = p * __builtin_amdgcn_rcpf(den);

  // pack a duplicated into f16x2 once; shfl the packed word in PV
  const _Float16 ah = (_Float16)a;
  half2v ad = {ah, ah};
  const uint32_t adu = __builtin_bit_cast(uint32_t, ad);

  // ---- PV: lane handles row qr, dims d0..d0+3 (d0 = (lane&7)*4) ----
  const int d0 = (lane & 7) * 4;
  const int gb = lane & 56;
  half2v o01 = {0, 0}, o23 = {0, 0};
  #pragma unroll
  for (int k = 0; k < 8; ++k) {
    const half2v ak2 = bch2((uint32_t)__shfl((int)adu, gb | k));
    const uint2 vv = *reinterpret_cast<const uint2*>(
        qkv + (size_t)(mbase + k * mstride) * 1536 + 1024 + chan0 + d0);
    o01 += ak2 * bch2(vv.x);
    o23 += ak2 * bch2(vv.y);
  }

  // ---- LePE: depthwise 3x3 on v (zero-pad SAME) at this lane's pixel ----
  const int hq = h0 + ((half == 0) ? qr : 0);
  const int wq = w0 + ((half == 0) ? 0 : qr);
  const float* lw = ((half == 0) ? lepe_h : lepe_v) + n * 32 + d0;
  half2v l01 = {0, 0}, l23 = {0, 0};
  #pragma unroll
  for (int dy = -1; dy <= 1; ++dy) {
    const int hh = hq + dy;
    if (hh < 0 || hh > 63) continue;
    #pragma unroll
    for (int dx = -1; dx <= 1; ++dx) {
      const int ww = wq + dx;
      if (ww < 0 || ww > 63) continue;
      const uint2 vv = *reinterpret_cast<const uint2*>(
          qkv + (size_t)(b * 4096 + hh * 64 + ww) * 1536 + 1024 + chan0 + d0);
      const float4 wf = *reinterpret_cast<const float4*>(
          lw + ((dy + 1) * 3 + (dx + 1)) * 256);
      const half2v w01 = pkrtz(wf.x, wf.y);
      const half2v w23 = pkrtz(wf.z, wf.w);
      l01 += w01 * bch2(vv.x);
      l23 += w23 * bch2(vv.y);
    }
  }

  const int mq = mbase + qr * mstride;
  const half2v r01 = o01 + l01;
  const half2v r23 = o23 + l23;
  uint2 r;
  r.x = __builtin_bit_cast(uint32_t, r01);
  r.y = __builtin_bit_cast(uint32_t, r23);
  *reinterpret_cast<uint2*>(outp + (size_t)mq * 512 + chan0 + d0) = r;
}

// ---------- launch ----------
extern "C" void kernel_launch(void* const* d_in, const int* in_sizes, int n_in,
                              void* d_out, int out_size, void* d_ws, size_t ws_size,
                              hipStream_t stream) {
  const float* x      = (const float*)d_in[0];   // (8, 4096, 512)
  const float* w_qkv  = (const float*)d_in[1];   // (1536, 512)
  const float* w_proj = (const float*)d_in[2];   // (512, 512)
  const float* b_proj = (const float*)d_in[3];   // (512,)
  const float* lepe_h = (const float*)d_in[4];   // (3,3,1,256)
  const float* lepe_v = (const float*)d_in[5];   // (3,3,1,256)
  float* out = (float*)d_out;                    // (8, 4096, 512) f32

  char* ws = (char*)d_ws;
  unsigned short* qkv_h   = (unsigned short*)ws;                    // 32768*1536 f16 (96 MB)
  unsigned short* xh      = (unsigned short*)(ws + 100663296);      // 32768*512  f16 (32 MB); reused as attn_out
  unsigned short* wqkv_h  = (unsigned short*)(ws + 134217728);      // 1536*512
  unsigned short* wproj_h = (unsigned short*)(ws + 135790592);      // 512*512

  // casts
  cvt_f32_f16<<<16384, 256, 0, stream>>>(x, xh, 4194304);
  cvt_f32_f16<<<768,   256, 0, stream>>>(w_qkv, wqkv_h, 196608);
  cvt_f32_f16<<<256,   256, 0, stream>>>(w_proj, wproj_h, 65536);

  // qkv = x @ w_qkv^T  -> f16
  gemm_bt<true><<<dim3(256, 12), 256, 0, stream>>>(
      xh, wqkv_h, qkv_h, nullptr, nullptr, 32768, 1536, 512);

  // stripe attention + LePE -> attn_out (overwrites xh region; xh is dead)
  attn_lepe<<<16384, 256, 0, stream>>>(qkv_h, lepe_h, lepe_v, xh);

  // out = attn_out @ w_proj^T + b_proj  -> f32
  gemm_bt<false><<<dim3(256, 4), 256, 0, stream>>>(
      xh, wproj_h, nullptr, out, b_proj, 32768, 512, 512);
}

// Round 4
// 211.796 us; speedup vs baseline: 1.0661x; 1.0602x over previous
//
#include <hip/hip_runtime.h>
#include <hip/hip_bf16.h>
#include <stdint.h>

// ---------- types ----------
typedef _Float16 half2v __attribute__((ext_vector_type(2)));
typedef _Float16 half8v __attribute__((ext_vector_type(8)));
typedef uint32_t u32x4  __attribute__((ext_vector_type(4)));
typedef float    f32x4  __attribute__((ext_vector_type(4)));

__device__ __forceinline__ unsigned short f2h(float f) {
  _Float16 h = (_Float16)f;
  return __builtin_bit_cast(unsigned short, h);
}
__device__ __forceinline__ half2v bch2(uint32_t u) {
  return __builtin_bit_cast(half2v, u);
}

// Window-major qkv layout. Element index (channel 0 of head n) for pixel (h,w),
// within one tensor's 32MB region (16M f16 elems; includes the half offset).
//  half 0 (horizontal stripes): [b][n][s=h>>3][w][qr=h&7][cc]
//  half 1 (vertical stripes):   [b][n][h][s=w>>3][qr=w&7][cc]  (s*256+qr*32 == w*32)
__device__ __forceinline__ int qkv_idx(int half, int b, int n, int h, int w) {
  int idx = half * 8388608 + (b * 8 + n) * 131072;
  idx += (half == 0) ? ((h >> 3) * 16384 + w * 256 + (h & 7) * 32)
                     : (h * 2048 + w * 32);
  return idx;
}

// async global->LDS, 16 bytes per lane. lbase must be wave-uniform.
#define GLOAD_LDS16(gsrc, lbase)                                          \
  __builtin_amdgcn_global_load_lds(                                       \
      (const __attribute__((address_space(1))) uint32_t*)(gsrc),          \
      (__attribute__((address_space(3))) uint32_t*)(lbase), 16, 0, 0)

// ---------- f32 -> f16 conversion (4 elems/thread) ----------
__global__ __launch_bounds__(256) void cvt_f32_f16(const float* __restrict__ in,
                                                   unsigned short* __restrict__ out,
                                                   int n4) {
  int i = blockIdx.x * 256 + threadIdx.x;
  if (i >= n4) return;
  float4 f = reinterpret_cast<const float4*>(in)[i];
  ushort4 u;
  u.x = f2h(f.x); u.y = f2h(f.y); u.z = f2h(f.z); u.w = f2h(f.w);
  reinterpret_cast<ushort4*>(out)[i] = u;
}

// ---------- f16 GEMM, C[m,n] = sum_k A[m,k]*B[n,k]  (A: MxK, B: NxK row-major)
// 128x128 tile, 4 waves (2x2), each wave 64x64 = 4x4 frags, MFMA 16x16x32 f16.
// MODE 0: f32 out + bias, token-major (GEMM2).
// MODE 1: f16 out scattered to window-major qkv regions (GEMM1, N=1536).
template<int MODE>
__global__ __launch_bounds__(256) void gemm_bt(
    const unsigned short* __restrict__ A,
    const unsigned short* __restrict__ B,
    unsigned short* __restrict__ Cq,
    float* __restrict__ Cf,
    const float* __restrict__ bias,
    int M, int N, int K)
{
  __shared__ unsigned short As[128 * 32];
  __shared__ unsigned short Bs[128 * 32];
  const int tid  = threadIdx.x;
  const int m0   = blockIdx.x * 128;
  const int n0   = blockIdx.y * 128;
  const int wave = tid >> 6, lane = tid & 63;
  const int wr = wave >> 1, wc = wave & 1;
  const int sr = tid >> 2;           // staging row 0..63
  const int sc = (tid & 3) * 8;      // staging col (8 f16 = 16B)
  const size_t aBase0 = (size_t)(m0 + sr) * K + sc;
  const size_t aBase1 = (size_t)(m0 + 64 + sr) * K + sc;
  const size_t bBase0 = (size_t)(n0 + sr) * K + sc;
  const size_t bBase1 = (size_t)(n0 + 64 + sr) * K + sc;
  char* ldsA = (char*)As + (tid & ~63) * 16;   // wave-uniform base + lane*16
  char* ldsB = (char*)Bs + (tid & ~63) * 16;

  f32x4 acc[4][4];
  const f32x4 zero = {0.f, 0.f, 0.f, 0.f};
  #pragma unroll
  for (int i = 0; i < 4; ++i)
    #pragma unroll
    for (int j = 0; j < 4; ++j) acc[i][j] = zero;

  const int lr = lane & 15;
  const int lk = (lane >> 4) * 8;

  for (int kt = 0; kt < K; kt += 32) {
    __syncthreads();
    GLOAD_LDS16(A + aBase0 + kt, ldsA);
    GLOAD_LDS16(A + aBase1 + kt, ldsA + 4096);
    GLOAD_LDS16(B + bBase0 + kt, ldsB);
    GLOAD_LDS16(B + bBase1 + kt, ldsB + 4096);
    __syncthreads();
    half8v af[4], bfr[4];
    #pragma unroll
    for (int i = 0; i < 4; ++i)
      af[i] = *reinterpret_cast<const half8v*>(As + (wr * 64 + i * 16 + lr) * 32 + lk);
    #pragma unroll
    for (int j = 0; j < 4; ++j)
      bfr[j] = *reinterpret_cast<const half8v*>(Bs + (wc * 64 + j * 16 + lr) * 32 + lk);
    #pragma unroll
    for (int i = 0; i < 4; ++i)
      #pragma unroll
      for (int j = 0; j < 4; ++j)
        acc[i][j] = __builtin_amdgcn_mfma_f32_16x16x32_f16(af[i], bfr[j], acc[i][j], 0, 0, 0);
  }

  const int cr = (lane >> 4) * 4;   // C/D: row = cr + t, col = cc
  const int cc = lane & 15;

  if constexpr (MODE == 0) {
    #pragma unroll
    for (int i = 0; i < 4; ++i) {
      #pragma unroll
      for (int j = 0; j < 4; ++j) {
        const int row = m0 + wr * 64 + i * 16 + cr;
        const int col = n0 + wc * 64 + j * 16 + cc;
        #pragma unroll
        for (int t = 0; t < 4; ++t)
          Cf[(size_t)(row + t) * N + col] = acc[i][j][t] + bias[col];
      }
    }
  } else {
    // token m = mb + w, w = i*16+cr+t in [0,64); (b, htok) uniform over the wave
    const int mb   = m0 + wr * 64;
    const int btok = mb >> 12;
    const int htok = (mb >> 6) & 63;
    #pragma unroll
    for (int j = 0; j < 4; ++j) {
      const int cb    = n0 + wc * 64 + j * 16;  // uniform; no tensor/half/head straddle
      const int tq    = cb >> 9;                // 0=q 1=k 2=v
      const int halfc = (cb >> 8) & 1;
      const int nn    = (cb & 255) >> 5;
      const int ccl   = (cb & 31) + cc;         // channel within head, 0..31
      const int wstride = halfc ? 32 : 256;
      int base = tq * 16777216 + halfc * 8388608 + (btok * 8 + nn) * 131072 + ccl;
      base += halfc ? (htok * 2048) : ((htok >> 3) * 16384 + (htok & 7) * 32);
      #pragma unroll
      for (int i = 0; i < 4; ++i) {
        #pragma unroll
        for (int t = 0; t < 4; ++t) {
          const int w = i * 16 + cr + t;
          Cq[base + w * wstride] = f2h(acc[i][j][t]);
        }
      }
    }
  }
}

// ---------- stripe attention + LePE on window-major qkv ----------
// qkvp: q region (32MB) | k region (32MB) | v region (32MB), f16, window-major.
// wlep: f16 LePE weights [half][tap(9)][256].
// outp: token-major 32768 x 512 f16.
__global__ __launch_bounds__(256) void attn_lepe(
    const unsigned short* __restrict__ qkvp,
    const unsigned short* __restrict__ wlep,
    unsigned short* __restrict__ outp)
{
  const int gw   = (int)((blockIdx.x * 256 + threadIdx.x) >> 6);
  const int lane = threadIdx.x & 63;
  const int half = gw >> 15;
  const int id   = gw & 32767;
  const int b    = id >> 12;
  const int n    = (id >> 9) & 7;
  int h0, w0;
  if (half == 0) { const int s = (id >> 6) & 7; h0 = s * 8; w0 = id & 63; }
  else           { const int s = id & 7; h0 = (id >> 3) & 63; w0 = s * 8; }
  const int winbase = qkv_idx(half, b, n, h0, w0);
  const unsigned short* qwin = qkvp + winbase;
  const unsigned short* kwin = qkvp + 16777216 + winbase;
  const unsigned short* vwin = qkvp + 33554432 + winbase;

  // ---- QK^T: lane (qr, kr); window rows are 32-elem contiguous ----
  const int qr = lane >> 3, kr = lane & 7;
  const unsigned short* qp = qwin + qr * 32;
  const unsigned short* kp = kwin + kr * 32;
  float s_val = 0.f;
  #pragma unroll
  for (int c = 0; c < 4; ++c) {
    u32x4 qv = *reinterpret_cast<const u32x4*>(qp + c * 8);
    u32x4 kv = *reinterpret_cast<const u32x4*>(kp + c * 8);
    #pragma unroll
    for (int e = 0; e < 4; ++e)
      s_val = __builtin_amdgcn_fdot2(bch2(qv[e]), bch2(kv[e]), s_val, false);
  }
  s_val *= 0.17677669529663687f;  // 1/sqrt(32)

  // ---- softmax over k within each 8-lane group (|s| small: no max pass) ----
  float p = __expf(s_val);
  float den = p;
  den += __shfl_xor(den, 1);
  den += __shfl_xor(den, 2);
  den += __shfl_xor(den, 4);
  const float a = p * __builtin_amdgcn_rcpf(den);
  const _Float16 ah = (_Float16)a;
  half2v ad = {ah, ah};
  const uint32_t adu = __builtin_bit_cast(uint32_t, ad);

  // ---- PV: lane (qr, d0); v row k is one 64B line for the whole wave ----
  const int d0 = (lane & 7) * 4;
  const int gb = lane & 56;
  half2v o01 = {0, 0}, o23 = {0, 0};
  #pragma unroll
  for (int k = 0; k < 8; ++k) {
    const half2v ak2 = bch2((uint32_t)__shfl((int)adu, gb | k));
    const uint2 vv = *reinterpret_cast<const uint2*>(vwin + k * 32 + d0);
    o01 += ak2 * bch2(vv.x);
    o23 += ak2 * bch2(vv.y);
  }

  // ---- LePE: depthwise 3x3 on v (zero-pad SAME); taps are contiguous blocks ----
  const int hq = h0 + ((half == 0) ? qr : 0);
  const int wq = w0 + ((half == 0) ? 0 : qr);
  const unsigned short* vplane = qkvp + 33554432;
  const unsigned short* wl = wlep + half * 2304 + n * 32 + d0;
  half2v l01 = {0, 0}, l23 = {0, 0};
  #pragma unroll
  for (int dy = -1; dy <= 1; ++dy) {
    #pragma unroll
    for (int dx = -1; dx <= 1; ++dx) {
      const int hh = hq + dy, ww = wq + dx;
      uint2 vv; vv.x = 0u; vv.y = 0u;
      if ((unsigned)hh < 64u && (unsigned)ww < 64u)
        vv = *reinterpret_cast<const uint2*>(vplane + qkv_idx(half, b, n, hh, ww) + d0);
      const uint2 wt = *reinterpret_cast<const uint2*>(wl + ((dy + 1) * 3 + dx + 1) * 256);
      l01 += bch2(wt.x) * bch2(vv.x);
      l23 += bch2(wt.y) * bch2(vv.y);
    }
  }

  // ---- store token-major for GEMM2 ----
  const int m = b * 4096 + hq * 64 + wq;
  const int chan0 = half * 256 + n * 32;
  const half2v r01 = o01 + l01;
  const half2v r23 = o23 + l23;
  uint2 r;
  r.x = __builtin_bit_cast(uint32_t, r01);
  r.y = __builtin_bit_cast(uint32_t, r23);
  *reinterpret_cast<uint2*>(outp + (size_t)m * 512 + chan0 + d0) = r;
}

// ---------- launch ----------
extern "C" void kernel_launch(void* const* d_in, const int* in_sizes, int n_in,
                              void* d_out, int out_size, void* d_ws, size_t ws_size,
                              hipStream_t stream) {
  const float* x      = (const float*)d_in[0];   // (8, 4096, 512)
  const float* w_qkv  = (const float*)d_in[1];   // (1536, 512)
  const float* w_proj = (const float*)d_in[2];   // (512, 512)
  const float* b_proj = (const float*)d_in[3];   // (512,)
  const float* lepe_h = (const float*)d_in[4];   // (3,3,1,256)
  const float* lepe_v = (const float*)d_in[5];   // (3,3,1,256)
  float* out = (float*)d_out;                    // (8, 4096, 512) f32

  char* ws = (char*)d_ws;
  unsigned short* qkv_p   = (unsigned short*)ws;                 // 96MB: q|k|v window-major
  unsigned short* xh      = (unsigned short*)(ws + 100663296);   // 32MB: x f16; reused as attn_out
  unsigned short* wqkv_h  = (unsigned short*)(ws + 134217728);   // 1536*512 f16
  unsigned short* wproj_h = (unsigned short*)(ws + 135790592);   // 512*512 f16
  unsigned short* wlep_h  = (unsigned short*)(ws + 136314880);   // 2*9*256 f16

  // casts
  cvt_f32_f16<<<16384, 256, 0, stream>>>(x, xh, 4194304);
  cvt_f32_f16<<<768,   256, 0, stream>>>(w_qkv, wqkv_h, 196608);
  cvt_f32_f16<<<256,   256, 0, stream>>>(w_proj, wproj_h, 65536);
  cvt_f32_f16<<<3,     256, 0, stream>>>(lepe_h, wlep_h, 576);
  cvt_f32_f16<<<3,     256, 0, stream>>>(lepe_v, wlep_h + 2304, 576);

  // qkv = x @ w_qkv^T -> window-major f16 regions
  gemm_bt<1><<<dim3(256, 12), 256, 0, stream>>>(
      xh, wqkv_h, qkv_p, nullptr, nullptr, 32768, 1536, 512);

  // stripe attention + LePE -> attn_out token-major (xh region; xh dead)
  attn_lepe<<<16384, 256, 0, stream>>>(qkv_p, wlep_h, xh);

  // out = attn_out @ w_proj^T + b_proj -> f32
  gemm_bt<0><<<dim3(256, 4), 256, 0, stream>>>(
      xh, wproj_h, nullptr, out, b_proj, 32768, 512, 512);
}